// Round 3
// baseline (1412.640 us; speedup 1.0000x reference)
//
#include <hip/hip_runtime.h>

// ===== problem constants =====
#define NH   16
#define HD   64
#define SQL  1024
#define SKL  2048
#define EMB  1024

typedef __bf16 bf16x8 __attribute__((ext_vector_type(8)));
typedef float  f32x4  __attribute__((ext_vector_type(4)));

__device__ __forceinline__ unsigned short f2bf(float f) {
  unsigned u = __builtin_bit_cast(unsigned, f);
  u += 0x7FFFu + ((u >> 16) & 1u);   // round-to-nearest-even
  return (unsigned short)(u >> 16);
}
__device__ __forceinline__ float bf2f(unsigned short h) {
  return __builtin_bit_cast(float, (unsigned)h << 16);
}

typedef __attribute__((address_space(1))) void gvoid_t;
typedef __attribute__((address_space(3))) void lvoid_t;

// async global->LDS, 16B per lane, dest = wave-uniform base + lane*16 (m97 pattern)
__device__ __forceinline__ void async_copy16(const void* g, void* l) {
  __builtin_amdgcn_global_load_lds((gvoid_t*)g, (lvoid_t*)l, 16, 0, 0);
}

// ===== weights fp32 -> bf16 =====
__global__ void cvtw_k(const float* __restrict__ w0, const float* __restrict__ w1,
                       const float* __restrict__ w2, const float* __restrict__ w3,
                       unsigned short* __restrict__ out)
{
  const int seg = blockIdx.y;
  const float* src = (seg == 0) ? w0 : ((seg == 1) ? w1 : ((seg == 2) ? w2 : w3));
  unsigned short* dst = out + (size_t)seg * 1024 * 1024;
  const int i = blockIdx.x * 256 + threadIdx.x;   // 131072 chunks of 8
  const float4 a  = ((const float4*)src)[2 * (size_t)i];
  const float4 b2 = ((const float4*)src)[2 * (size_t)i + 1];
  uint4 o;
  o.x = f2bf(a.x)  | ((unsigned)f2bf(a.y)  << 16);
  o.y = f2bf(a.z)  | ((unsigned)f2bf(a.w)  << 16);
  o.z = f2bf(b2.x) | ((unsigned)f2bf(b2.y) << 16);
  o.w = f2bf(b2.z) | ((unsigned)f2bf(b2.w) << 16);
  ((uint4*)dst)[i] = o;
}

// ===== GEMM: C = A @ W^T (+bias)(+resid) =====
// A: [M,1024] fp32 (AF32=1, converted in staging) or bf16 (AF32=0).
// W: [1024,1024] bf16. 128x128 tile, BK=64, 4 waves (2x2 of 64x64).
// LINEAR LDS (m97-verified pattern, no swizzle).
// MODE 0: bf16 out, permuted [B,H,S,D], scaled. MODE 1: f32 out + bias + residual.
template<int MODE, int AF32>
__global__ __launch_bounds__(256, 2)
void gemm_bt(const void* __restrict__ Ain, const unsigned short* __restrict__ Bw,
             const float* __restrict__ bias, void* __restrict__ Cout,
             const float* __restrict__ resid, int Slog, float scale)
{
  __shared__ __attribute__((aligned(16))) unsigned short sA[128 * 64];
  __shared__ __attribute__((aligned(16))) unsigned short sB[128 * 64];

  const int tid = threadIdx.x;
  const int lane = tid & 63, w = tid >> 6;
  const int g = lane >> 4, lr = lane & 15;
  const int wm = w >> 1, wn = w & 1;
  const int bm = blockIdx.x * 128, bn = blockIdx.y * 128;

  f32x4 acc[4][4] = {};

  for (int k0 = 0; k0 < 1024; k0 += 64) {
    // --- stage B tile (bf16 weights) via global_load_lds, linear ---
#pragma unroll
    for (int i = 0; i < 4; ++i) {
      const int chunk = (i * 4 + w) * 64 + lane;   // 0..1023
      const int o = chunk * 16;                    // linear LDS byte offset
      const int row = o >> 7;                      // 128B per row
      const size_t gb = (size_t)(bn + row) * 1024 + k0 + ((o & 127) >> 1);
      async_copy16(Bw + gb, sB + (i * 4 + w) * 512);
    }
    // --- stage A tile ---
    if (AF32) {
      // fp32 global -> bf16 LDS, reg-staged
#pragma unroll
      for (int i = 0; i < 4; ++i) {
        const int c = i * 256 + tid;               // 0..1023
        const int row = c >> 3, c8 = c & 7;
        const float* src = (const float*)Ain + (size_t)(bm + row) * 1024 + k0 + c8 * 8;
        const float4 f0 = *(const float4*)src;
        const float4 f1 = *(const float4*)(src + 4);
        uint4 o;
        o.x = f2bf(f0.x) | ((unsigned)f2bf(f0.y) << 16);
        o.y = f2bf(f0.z) | ((unsigned)f2bf(f0.w) << 16);
        o.z = f2bf(f1.x) | ((unsigned)f2bf(f1.y) << 16);
        o.w = f2bf(f1.z) | ((unsigned)f2bf(f1.w) << 16);
        *(uint4*)((char*)sA + c * 16) = o;
      }
    } else {
#pragma unroll
      for (int i = 0; i < 4; ++i) {
        const int chunk = (i * 4 + w) * 64 + lane;
        const int o = chunk * 16;
        const int row = o >> 7;
        const size_t ga = (size_t)(bm + row) * 1024 + k0 + ((o & 127) >> 1);
        async_copy16((const unsigned short*)Ain + ga, sA + (i * 4 + w) * 512);
      }
    }
    __syncthreads();
#pragma unroll
    for (int kc = 0; kc < 2; ++kc) {
      const int kb = kc * 64 + g * 16;             // byte offset within 128B row
      bf16x8 af[4], bf[4];
#pragma unroll
      for (int mi = 0; mi < 4; ++mi) {
        const int r = wm * 64 + mi * 16 + lr;
        af[mi] = *(const bf16x8*)((const char*)sA + ((r << 7) | kb));
      }
#pragma unroll
      for (int ni = 0; ni < 4; ++ni) {
        const int r = wn * 64 + ni * 16 + lr;
        bf[ni] = *(const bf16x8*)((const char*)sB + ((r << 7) | kb));
      }
#pragma unroll
      for (int mi = 0; mi < 4; ++mi)
#pragma unroll
        for (int ni = 0; ni < 4; ++ni)
          acc[mi][ni] = __builtin_amdgcn_mfma_f32_16x16x32_bf16(af[mi], bf[ni], acc[mi][ni], 0, 0, 0);
    }
    __syncthreads();
  }

  if (MODE == 0) {
    unsigned short* O = (unsigned short*)Cout;
    const int S = 1 << Slog;
#pragma unroll
    for (int ni = 0; ni < 4; ++ni) {
      const int col = bn + wn * 64 + ni * 16 + lr;
      const float bv = bias[col];
      const int hh = col >> 6, d = col & 63;
#pragma unroll
      for (int mi = 0; mi < 4; ++mi) {
#pragma unroll
        for (int j = 0; j < 4; ++j) {
          const int row = bm + wm * 64 + mi * 16 + g * 4 + j;
          const int bI = row >> Slog, s2 = row & (S - 1);
          O[(((size_t)(bI * NH + hh)) * S + s2) * HD + d] = f2bf((acc[mi][ni][j] + bv) * scale);
        }
      }
    }
  } else {
    float* O = (float*)Cout;
#pragma unroll
    for (int ni = 0; ni < 4; ++ni) {
      const int col = bn + wn * 64 + ni * 16 + lr;
      const float bv = bias[col];
#pragma unroll
      for (int mi = 0; mi < 4; ++mi) {
#pragma unroll
        for (int j = 0; j < 4; ++j) {
          const int row = bm + wm * 64 + mi * 16 + g * 4 + j;
          const size_t idx = (size_t)row * 1024 + col;
          O[idx] = acc[mi][ni][j] + bv + resid[idx];
        }
      }
    }
  }
}

// ===== SIMPLE fp32 flash attention (bisection kernel) =====
// One thread per q-row. Block = 256 threads = 256 q-rows of one (b,h).
// K/V tiles (128 rows) staged as fp32 in LDS, linear & coalesced.
// Scalar online softmax per thread. Near-zero bug surface.
__global__ __launch_bounds__(256, 1)
void attn_simple_k(const unsigned short* __restrict__ Qp, const unsigned short* __restrict__ Kp,
                   const unsigned short* __restrict__ Vp, unsigned short* __restrict__ ctx)
{
  __shared__ float sKf[128 * 64];
  __shared__ float sVf[128 * 64];

  const int tid = threadIdx.x;
  const int b = blockIdx.z, h = blockIdx.y;
  const int qrow = blockIdx.x * 256 + tid;
  const size_t qbase  = ((size_t)(b * NH + h)) * SQL * HD;
  const size_t kvbase = ((size_t)(b * NH + h)) * SKL * HD;

  float qreg[HD];
#pragma unroll
  for (int d = 0; d < HD; ++d)
    qreg[d] = bf2f(Qp[qbase + (size_t)qrow * HD + d]);   // pre-scaled by 1/8

  float m = -__builtin_inff(), l = 0.f;
  float cacc[HD];
#pragma unroll
  for (int d = 0; d < HD; ++d) cacc[d] = 0.f;

  for (int kt = 0; kt < SKL / 128; ++kt) {
    // stage 128x64 K and V tiles as fp32 (8192 elements each; 32 per thread)
#pragma unroll
    for (int c = 0; c < 32; ++c) {
      const int f = c * 256 + tid;
      sKf[f] = bf2f(Kp[kvbase + (size_t)kt * 8192 + f]);
      sVf[f] = bf2f(Vp[kvbase + (size_t)kt * 8192 + f]);
    }
    __syncthreads();

    for (int kk = 0; kk < 128; ++kk) {
      float s = 0.f;
#pragma unroll
      for (int d = 0; d < HD; ++d) s += qreg[d] * sKf[kk * HD + d];
      if (s > m) {                       // rescale history
        const float cfac = __expf(m - s);
        l *= cfac;
#pragma unroll
        for (int d = 0; d < HD; ++d) cacc[d] *= cfac;
        m = s;
      }
      const float p = __expf(s - m);
      l += p;
#pragma unroll
      for (int d = 0; d < HD; ++d) cacc[d] += p * sVf[kk * HD + d];
    }
    __syncthreads();
  }

  const float inv = 1.0f / l;
#pragma unroll
  for (int d = 0; d < HD; ++d)
    ctx[((size_t)b * SQL + qrow) * EMB + h * HD + d] = f2bf(cacc[d] * inv);
}

// ===== residual + LayerNorm: one block per row of 1024 =====
__global__ __launch_bounds__(256)
void ln_k(const float* __restrict__ x, const float* __restrict__ gm,
          const float* __restrict__ bt, float* __restrict__ out)
{
  const int row = blockIdx.x, t = threadIdx.x;
  const float4 v = ((const float4*)(x + (size_t)row * 1024))[t];
  float s  = v.x + v.y + v.z + v.w;
  float ss = v.x * v.x + v.y * v.y + v.z * v.z + v.w * v.w;
#pragma unroll
  for (int off = 32; off > 0; off >>= 1) {
    s  += __shfl_xor(s, off);
    ss += __shfl_xor(ss, off);
  }
  __shared__ float red[8];
  const int wv = t >> 6, lane = t & 63;
  if (lane == 0) { red[wv] = s; red[4 + wv] = ss; }
  __syncthreads();
  s  = red[0] + red[1] + red[2] + red[3];
  ss = red[4] + red[5] + red[6] + red[7];
  const float mu  = s * (1.0f / 1024.0f);
  const float var = ss * (1.0f / 1024.0f) - mu * mu;
  const float r = rsqrtf(var + 1e-5f);
  const float4 gg = ((const float4*)gm)[t];
  const float4 bb = ((const float4*)bt)[t];
  float4 o;
  o.x = (v.x - mu) * r * gg.x + bb.x;
  o.y = (v.y - mu) * r * gg.y + bb.y;
  o.z = (v.z - mu) * r * gg.z + bb.z;
  o.w = (v.w - mu) * r * gg.w + bb.w;
  ((float4*)(out + (size_t)row * 1024))[t] = o;
}

extern "C" void kernel_launch(void* const* d_in, const int* in_sizes, int n_in,
                              void* d_out, int out_size, void* d_ws, size_t ws_size,
                              hipStream_t stream)
{
  (void)in_sizes; (void)n_in; (void)out_size; (void)ws_size;
  const float* query = (const float*)d_in[0];
  const float* key   = (const float*)d_in[1];
  const float* value = (const float*)d_in[2];
  const float* Wq = (const float*)d_in[3];
  const float* bq = (const float*)d_in[4];
  const float* Wk = (const float*)d_in[5];
  const float* bk = (const float*)d_in[6];
  const float* Wv = (const float*)d_in[7];
  const float* bv = (const float*)d_in[8];
  const float* Wo = (const float*)d_in[9];
  const float* bo = (const float*)d_in[10];
  const float* gamma = (const float*)d_in[11];
  const float* beta  = (const float*)d_in[12];

  // workspace layout (peak 56 MB):
  // [0,8M):   Wb  (4 weights bf16)
  // [8,16M):  Qp  bf16 [B,H,SQ,D]   -- later (with Kp region) xb f32 [8,24M)
  // [16,32M): Kp  bf16 [B,H,SK,D]
  // [32,48M): Vp  bf16 [B,H,SK,D]
  // [48,56M): ctx bf16 [B,SQ,E]
  char* ws = (char*)d_ws;
  unsigned short* Wb  = (unsigned short*)(ws);
  unsigned short* Qp  = (unsigned short*)(ws + (8ull  << 20));
  float*          xb  = (float*)         (ws + (8ull  << 20));
  unsigned short* Kp  = (unsigned short*)(ws + (16ull << 20));
  unsigned short* Vp  = (unsigned short*)(ws + (32ull << 20));
  unsigned short* ctx = (unsigned short*)(ws + (48ull << 20));

  cvtw_k<<<dim3(512, 4), 256, 0, stream>>>(Wq, Wk, Wv, Wo, Wb);
  // projections from fp32 activations (Q pre-scaled by 1/sqrt(HD)=0.125)
  gemm_bt<0, 1><<<dim3(32, 8), 256, 0, stream>>>(query, Wb,               bq, Qp, nullptr, 10, 0.125f);
  gemm_bt<0, 1><<<dim3(64, 8), 256, 0, stream>>>(key,   Wb + (1u << 20),  bk, Kp, nullptr, 11, 1.0f);
  gemm_bt<0, 1><<<dim3(64, 8), 256, 0, stream>>>(value, Wb + (2u << 20),  bv, Vp, nullptr, 11, 1.0f);
  attn_simple_k<<<dim3(4, NH, 4), 256, 0, stream>>>(Qp, Kp, Vp, ctx);
  // out projection + bias + residual (f32); A = ctx (bf16)
  gemm_bt<1, 0><<<dim3(32, 8), 256, 0, stream>>>(ctx, Wb + (3u << 20),    bo, xb, query, 10, 1.0f);
  ln_k<<<dim3(4096), 256, 0, stream>>>(xb, gamma, beta, (float*)d_out);
}

// Round 4
// 432.310 us; speedup vs baseline: 3.2677x; 3.2677x over previous
//
#include <hip/hip_runtime.h>

// ===== problem constants =====
#define NH   16
#define HD   64
#define SQL  1024
#define SKL  2048
#define EMB  1024

typedef __bf16 bf16x8 __attribute__((ext_vector_type(8)));
typedef float  f32x4  __attribute__((ext_vector_type(4)));

#define LOG2E 1.44269504088896f

__device__ __forceinline__ unsigned short f2bf(float f) {
  unsigned u = __builtin_bit_cast(unsigned, f);
  u += 0x7FFFu + ((u >> 16) & 1u);   // round-to-nearest-even
  return (unsigned short)(u >> 16);
}
__device__ __forceinline__ __bf16 f2bf16(float f) {
  return __builtin_bit_cast(__bf16, f2bf(f));
}

typedef __attribute__((address_space(1))) void gvoid_t;
typedef __attribute__((address_space(3))) void lvoid_t;

// async global->LDS, 16B per lane, dest = wave-uniform base + lane*16 (m97 pattern)
__device__ __forceinline__ void async_copy16(const void* g, void* l) {
  __builtin_amdgcn_global_load_lds((gvoid_t*)g, (lvoid_t*)l, 16, 0, 0);
}

// ===== weights fp32 -> bf16 =====
__global__ void cvtw_k(const float* __restrict__ w0, const float* __restrict__ w1,
                       const float* __restrict__ w2, const float* __restrict__ w3,
                       unsigned short* __restrict__ out)
{
  const int seg = blockIdx.y;
  const float* src = (seg == 0) ? w0 : ((seg == 1) ? w1 : ((seg == 2) ? w2 : w3));
  unsigned short* dst = out + (size_t)seg * 1024 * 1024;
  const int i = blockIdx.x * 256 + threadIdx.x;   // 131072 chunks of 8
  const float4 a  = ((const float4*)src)[2 * (size_t)i];
  const float4 b2 = ((const float4*)src)[2 * (size_t)i + 1];
  uint4 o;
  o.x = f2bf(a.x)  | ((unsigned)f2bf(a.y)  << 16);
  o.y = f2bf(a.z)  | ((unsigned)f2bf(a.w)  << 16);
  o.z = f2bf(b2.x) | ((unsigned)f2bf(b2.y) << 16);
  o.w = f2bf(b2.z) | ((unsigned)f2bf(b2.w) << 16);
  ((uint4*)dst)[i] = o;
}

// ===== GEMM: C = A @ W^T (+bias)(+resid) ===== (UNCHANGED from passing round 3)
// A: [M,1024] fp32 (AF32=1, converted in staging) or bf16 (AF32=0).
// W: [1024,1024] bf16. 128x128 tile, BK=64, 4 waves (2x2 of 64x64).
// MODE 0: bf16 out, permuted [B,H,S,D], scaled. MODE 1: f32 out + bias + residual.
template<int MODE, int AF32>
__global__ __launch_bounds__(256, 2)
void gemm_bt(const void* __restrict__ Ain, const unsigned short* __restrict__ Bw,
             const float* __restrict__ bias, void* __restrict__ Cout,
             const float* __restrict__ resid, int Slog, float scale)
{
  __shared__ __attribute__((aligned(16))) unsigned short sA[128 * 64];
  __shared__ __attribute__((aligned(16))) unsigned short sB[128 * 64];

  const int tid = threadIdx.x;
  const int lane = tid & 63, w = tid >> 6;
  const int g = lane >> 4, lr = lane & 15;
  const int wm = w >> 1, wn = w & 1;
  const int bm = blockIdx.x * 128, bn = blockIdx.y * 128;

  f32x4 acc[4][4] = {};

  for (int k0 = 0; k0 < 1024; k0 += 64) {
#pragma unroll
    for (int i = 0; i < 4; ++i) {
      const int chunk = (i * 4 + w) * 64 + lane;   // 0..1023
      const int o = chunk * 16;                    // linear LDS byte offset
      const int row = o >> 7;                      // 128B per row
      const size_t gb = (size_t)(bn + row) * 1024 + k0 + ((o & 127) >> 1);
      async_copy16(Bw + gb, sB + (i * 4 + w) * 512);
    }
    if (AF32) {
#pragma unroll
      for (int i = 0; i < 4; ++i) {
        const int c = i * 256 + tid;               // 0..1023
        const int row = c >> 3, c8 = c & 7;
        const float* src = (const float*)Ain + (size_t)(bm + row) * 1024 + k0 + c8 * 8;
        const float4 f0 = *(const float4*)src;
        const float4 f1 = *(const float4*)(src + 4);
        uint4 o;
        o.x = f2bf(f0.x) | ((unsigned)f2bf(f0.y) << 16);
        o.y = f2bf(f0.z) | ((unsigned)f2bf(f0.w) << 16);
        o.z = f2bf(f1.x) | ((unsigned)f2bf(f1.y) << 16);
        o.w = f2bf(f1.z) | ((unsigned)f2bf(f1.w) << 16);
        *(uint4*)((char*)sA + c * 16) = o;
      }
    } else {
#pragma unroll
      for (int i = 0; i < 4; ++i) {
        const int chunk = (i * 4 + w) * 64 + lane;
        const int o = chunk * 16;
        const int row = o >> 7;
        const size_t ga = (size_t)(bm + row) * 1024 + k0 + ((o & 127) >> 1);
        async_copy16((const unsigned short*)Ain + ga, sA + (i * 4 + w) * 512);
      }
    }
    __syncthreads();
#pragma unroll
    for (int kc = 0; kc < 2; ++kc) {
      const int kb = kc * 64 + g * 16;             // byte offset within 128B row
      bf16x8 af[4], bf[4];
#pragma unroll
      for (int mi = 0; mi < 4; ++mi) {
        const int r = wm * 64 + mi * 16 + lr;
        af[mi] = *(const bf16x8*)((const char*)sA + ((r << 7) | kb));
      }
#pragma unroll
      for (int ni = 0; ni < 4; ++ni) {
        const int r = wn * 64 + ni * 16 + lr;
        bf[ni] = *(const bf16x8*)((const char*)sB + ((r << 7) | kb));
      }
#pragma unroll
      for (int mi = 0; mi < 4; ++mi)
#pragma unroll
        for (int ni = 0; ni < 4; ++ni)
          acc[mi][ni] = __builtin_amdgcn_mfma_f32_16x16x32_bf16(af[mi], bf[ni], acc[mi][ni], 0, 0, 0);
    }
    __syncthreads();
  }

  if (MODE == 0) {
    unsigned short* O = (unsigned short*)Cout;
    const int S = 1 << Slog;
#pragma unroll
    for (int ni = 0; ni < 4; ++ni) {
      const int col = bn + wn * 64 + ni * 16 + lr;
      const float bv = bias[col];
      const int hh = col >> 6, d = col & 63;
#pragma unroll
      for (int mi = 0; mi < 4; ++mi) {
#pragma unroll
        for (int j = 0; j < 4; ++j) {
          const int row = bm + wm * 64 + mi * 16 + g * 4 + j;
          const int bI = row >> Slog, s2 = row & (S - 1);
          O[(((size_t)(bI * NH + hh)) * S + s2) * HD + d] = f2bf((acc[mi][ni][j] + bv) * scale);
        }
      }
    }
  } else {
    float* O = (float*)Cout;
#pragma unroll
    for (int ni = 0; ni < 4; ++ni) {
      const int col = bn + wn * 64 + ni * 16 + lr;
      const float bv = bias[col];
#pragma unroll
      for (int mi = 0; mi < 4; ++mi) {
#pragma unroll
        for (int j = 0; j < 4; ++j) {
          const int row = bm + wm * 64 + mi * 16 + g * 4 + j;
          const size_t idx = (size_t)row * 1024 + col;
          O[idx] = acc[mi][ni][j] + bv + resid[idx];
        }
      }
    }
  }
}

// ===== MFMA flash attention (fixed) =====
// Fix vs rounds 1/2: the softmax->PV round trip of P through LDS had NO barrier
// and used TBAA-incompatible types (ushort stores, __bf16 vector loads) -> the
// compiler could hoist the P ds_reads above the P ds_writes. Now: all softmax/V
// LDS buffers are __bf16-typed, and a __syncthreads() separates the P writes
// from the PV reads (barrier = compiler memory fence + HW ordering).
__global__ __launch_bounds__(256, 2)
void attn_k(const unsigned short* __restrict__ Qp, const unsigned short* __restrict__ Kp,
            const unsigned short* __restrict__ Vp, unsigned short* __restrict__ ctx)
{
  __shared__ __attribute__((aligned(16))) unsigned short sK[128 * 64];
  __shared__ __attribute__((aligned(16))) __bf16 sVt[64 * 136];
  __shared__ __attribute__((aligned(16))) __bf16 sP[4][32 * 136];

  const int tid = threadIdx.x, lane = tid & 63, w = tid >> 6;
  const int g = lane >> 4, lr = lane & 15;
  const int b = blockIdx.z, h = blockIdx.y;
  const int q0 = blockIdx.x * 128 + w * 32;
  const size_t qbase  = ((size_t)(b * NH + h)) * SQL * HD;
  const size_t kvbase = ((size_t)(b * NH + h)) * SKL * HD;

  // Q fragments live in registers (pre-scaled by 1/8 at projection)
  bf16x8 aq[2][2];
#pragma unroll
  for (int mi = 0; mi < 2; ++mi)
#pragma unroll
    for (int kc = 0; kc < 2; ++kc)
      aq[mi][kc] = *(const bf16x8*)(Qp + qbase + (size_t)(q0 + mi * 16 + lr) * HD + kc * 32 + g * 8);

  f32x4 c[2][4] = {};
  float mrun[2][4], lrun[2][4];
#pragma unroll
  for (int mi = 0; mi < 2; ++mi)
#pragma unroll
    for (int j = 0; j < 4; ++j) { mrun[mi][j] = -__builtin_inff(); lrun[mi][j] = 0.f; }

  for (int kt = 0; kt < SKL / 128; ++kt) {
    // stage K tile [128][64] linear via global_load_lds
#pragma unroll
    for (int i = 0; i < 4; ++i) {
      const int chunk = (i * 4 + w) * 64 + lane;
      const int o = chunk * 16;
      const int row = o >> 7;
      async_copy16(Kp + kvbase + (size_t)(kt * 128 + row) * HD + ((o & 127) >> 1),
                   sK + (i * 4 + w) * 512);
    }
    // stage V transposed: sVt[d][k], padded stride 136
#pragma unroll
    for (int i = 0; i < 4; ++i) {
      const int chunk = i * 256 + tid;
      const int k = chunk & 127, dblk = chunk >> 7;
      bf16x8 v = *(const bf16x8*)(Vp + kvbase + (size_t)(kt * 128 + k) * HD + dblk * 8);
#pragma unroll
      for (int j = 0; j < 8; ++j)
        sVt[(dblk * 8 + j) * 136 + k] = v[j];
    }
    __syncthreads();   // staging visible (drains global_load_lds too)

    // S = Q K^T, 32 q-rows x 128 k-cols per wave
    f32x4 s[2][8] = {};
#pragma unroll
    for (int kc = 0; kc < 2; ++kc) {
      const int kb = kc * 64 + g * 16;
#pragma unroll
      for (int ni = 0; ni < 8; ++ni) {
        const int r = ni * 16 + lr;
        bf16x8 bk = *(const bf16x8*)((const char*)sK + ((r << 7) | kb));
        s[0][ni] = __builtin_amdgcn_mfma_f32_16x16x32_bf16(aq[0][kc], bk, s[0][ni], 0, 0, 0);
        s[1][ni] = __builtin_amdgcn_mfma_f32_16x16x32_bf16(aq[1][kc], bk, s[1][ni], 0, 0, 0);
      }
    }

    // online softmax, wave-parallel (row = mi*16 + 4g + j; 16 lanes lr share a row)
#pragma unroll
    for (int mi = 0; mi < 2; ++mi) {
#pragma unroll
      for (int j = 0; j < 4; ++j) {
        float rm = s[mi][0][j];
#pragma unroll
        for (int ni = 1; ni < 8; ++ni) rm = fmaxf(rm, s[mi][ni][j]);
#pragma unroll
        for (int off = 1; off < 16; off <<= 1) rm = fmaxf(rm, __shfl_xor(rm, off));
        const float mnew = fmaxf(mrun[mi][j], rm);
        const float sc = __builtin_exp2f((mrun[mi][j] - mnew) * LOG2E);
        mrun[mi][j] = mnew;
#pragma unroll
        for (int nd = 0; nd < 4; ++nd) c[mi][nd][j] *= sc;
        float rs = 0.f;
#pragma unroll
        for (int ni = 0; ni < 8; ++ni) {
          const float p = __builtin_exp2f((s[mi][ni][j] - mnew) * LOG2E);
          rs += p;
          sP[w][(mi * 16 + g * 4 + j) * 136 + ni * 16 + lr] = f2bf16(p);
        }
#pragma unroll
        for (int off = 1; off < 16; off <<= 1) rs += __shfl_xor(rs, off);
        lrun[mi][j] = lrun[mi][j] * sc + rs;
      }
    }
    __syncthreads();   // *** order P writes before PV reads (the round-1/2 bug) ***

    // ctx += P @ V
#pragma unroll
    for (int kc = 0; kc < 4; ++kc) {
      const int ko = kc * 32 + g * 8;
      bf16x8 pa[2];
#pragma unroll
      for (int mi = 0; mi < 2; ++mi)
        pa[mi] = *(const bf16x8*)(&sP[w][(mi * 16 + lr) * 136 + ko]);
#pragma unroll
      for (int nd = 0; nd < 4; ++nd) {
        bf16x8 vf = *(const bf16x8*)(&sVt[(nd * 16 + lr) * 136 + ko]);
        c[0][nd] = __builtin_amdgcn_mfma_f32_16x16x32_bf16(pa[0], vf, c[0][nd], 0, 0, 0);
        c[1][nd] = __builtin_amdgcn_mfma_f32_16x16x32_bf16(pa[1], vf, c[1][nd], 0, 0, 0);
      }
    }
    __syncthreads();   // protect sK/sVt before next iteration's staging
  }

  // finalize: ctx / l, write [B, SQ, E] bf16
#pragma unroll
  for (int mi = 0; mi < 2; ++mi)
#pragma unroll
    for (int j = 0; j < 4; ++j) {
      const float inv = 1.0f / lrun[mi][j];
      const int qrow = q0 + mi * 16 + g * 4 + j;
#pragma unroll
      for (int nd = 0; nd < 4; ++nd) {
        const int d = nd * 16 + lr;
        ctx[((size_t)b * SQL + qrow) * EMB + h * HD + d] = f2bf(c[mi][nd][j] * inv);
      }
    }
}

// ===== residual + LayerNorm: one block per row of 1024 =====
__global__ __launch_bounds__(256)
void ln_k(const float* __restrict__ x, const float* __restrict__ gm,
          const float* __restrict__ bt, float* __restrict__ out)
{
  const int row = blockIdx.x, t = threadIdx.x;
  const float4 v = ((const float4*)(x + (size_t)row * 1024))[t];
  float s  = v.x + v.y + v.z + v.w;
  float ss = v.x * v.x + v.y * v.y + v.z * v.z + v.w * v.w;
#pragma unroll
  for (int off = 32; off > 0; off >>= 1) {
    s  += __shfl_xor(s, off);
    ss += __shfl_xor(ss, off);
  }
  __shared__ float red[8];
  const int wv = t >> 6, lane = t & 63;
  if (lane == 0) { red[wv] = s; red[4 + wv] = ss; }
  __syncthreads();
  s  = red[0] + red[1] + red[2] + red[3];
  ss = red[4] + red[5] + red[6] + red[7];
  const float mu  = s * (1.0f / 1024.0f);
  const float var = ss * (1.0f / 1024.0f) - mu * mu;
  const float r = rsqrtf(var + 1e-5f);
  const float4 gg = ((const float4*)gm)[t];
  const float4 bb = ((const float4*)bt)[t];
  float4 o;
  o.x = (v.x - mu) * r * gg.x + bb.x;
  o.y = (v.y - mu) * r * gg.y + bb.y;
  o.z = (v.z - mu) * r * gg.z + bb.z;
  o.w = (v.w - mu) * r * gg.w + bb.w;
  ((float4*)(out + (size_t)row * 1024))[t] = o;
}

extern "C" void kernel_launch(void* const* d_in, const int* in_sizes, int n_in,
                              void* d_out, int out_size, void* d_ws, size_t ws_size,
                              hipStream_t stream)
{
  (void)in_sizes; (void)n_in; (void)out_size; (void)ws_size;
  const float* query = (const float*)d_in[0];
  const float* key   = (const float*)d_in[1];
  const float* value = (const float*)d_in[2];
  const float* Wq = (const float*)d_in[3];
  const float* bq = (const float*)d_in[4];
  const float* Wk = (const float*)d_in[5];
  const float* bk = (const float*)d_in[6];
  const float* Wv = (const float*)d_in[7];
  const float* bv = (const float*)d_in[8];
  const float* Wo = (const float*)d_in[9];
  const float* bo = (const float*)d_in[10];
  const float* gamma = (const float*)d_in[11];
  const float* beta  = (const float*)d_in[12];

  // workspace layout (peak 56 MB):
  // [0,8M):   Wb  (4 weights bf16)
  // [8,16M):  Qp  bf16 [B,H,SQ,D]   -- later (with Kp region) xb f32 [8,24M)
  // [16,32M): Kp  bf16 [B,H,SK,D]
  // [32,48M): Vp  bf16 [B,H,SK,D]
  // [48,56M): ctx bf16 [B,SQ,E]
  char* ws = (char*)d_ws;
  unsigned short* Wb  = (unsigned short*)(ws);
  unsigned short* Qp  = (unsigned short*)(ws + (8ull  << 20));
  float*          xb  = (float*)         (ws + (8ull  << 20));
  unsigned short* Kp  = (unsigned short*)(ws + (16ull << 20));
  unsigned short* Vp  = (unsigned short*)(ws + (32ull << 20));
  unsigned short* ctx = (unsigned short*)(ws + (48ull << 20));

  cvtw_k<<<dim3(512, 4), 256, 0, stream>>>(Wq, Wk, Wv, Wo, Wb);
  // projections from fp32 activations (Q pre-scaled by 1/sqrt(HD)=0.125)
  gemm_bt<0, 1><<<dim3(32, 8), 256, 0, stream>>>(query, Wb,               bq, Qp, nullptr, 10, 0.125f);
  gemm_bt<0, 1><<<dim3(64, 8), 256, 0, stream>>>(key,   Wb + (1u << 20),  bk, Kp, nullptr, 11, 1.0f);
  gemm_bt<0, 1><<<dim3(64, 8), 256, 0, stream>>>(value, Wb + (2u << 20),  bv, Vp, nullptr, 11, 1.0f);
  attn_k<<<dim3(8, NH, 4), 256, 0, stream>>>(Qp, Kp, Vp, ctx);
  // out projection + bias + residual (f32); A = ctx (bf16)
  gemm_bt<1, 0><<<dim3(32, 8), 256, 0, stream>>>(ctx, Wb + (3u << 20),    bo, xb, query, 10, 1.0f);
  ln_k<<<dim3(4096), 256, 0, stream>>>(xb, gamma, beta, (float*)d_out);
}

// Round 5
// 395.417 us; speedup vs baseline: 3.5725x; 1.0933x over previous
//
#include <hip/hip_runtime.h>

// ===== problem constants =====
#define NH   16
#define HD   64
#define SQL  1024
#define SKL  2048
#define EMB  1024

typedef __bf16 bf16x8 __attribute__((ext_vector_type(8)));
typedef float  f32x4  __attribute__((ext_vector_type(4)));

#define LOG2E 1.44269504088896f

__device__ __forceinline__ unsigned short f2bf(float f) {
  unsigned u = __builtin_bit_cast(unsigned, f);
  u += 0x7FFFu + ((u >> 16) & 1u);   // round-to-nearest-even
  return (unsigned short)(u >> 16);
}
__device__ __forceinline__ __bf16 f2bf16(float f) {
  return __builtin_bit_cast(__bf16, f2bf(f));
}

typedef __attribute__((address_space(1))) void gvoid_t;
typedef __attribute__((address_space(3))) void lvoid_t;

// async global->LDS, 16B per lane, dest = wave-uniform base + lane*16 (m97 pattern)
__device__ __forceinline__ void async_copy16(const void* g, void* l) {
  __builtin_amdgcn_global_load_lds((gvoid_t*)g, (lvoid_t*)l, 16, 0, 0);
}

// ===== activations fp32 -> bf16 =====
__global__ void cvt3_k(const float* __restrict__ q, const float* __restrict__ k,
                       const float* __restrict__ v, unsigned short* __restrict__ qb,
                       unsigned short* __restrict__ kb, unsigned short* __restrict__ vb)
{
  const int seg = blockIdx.y;
  const float* src = (seg == 0) ? q : ((seg == 1) ? k : v);
  unsigned short* dst = (seg == 0) ? qb : ((seg == 1) ? kb : vb);
  const int n8 = (seg == 0) ? (4 * 1024 * 1024 / 8) : (8 * 1024 * 1024 / 8);
  const int i = blockIdx.x * 256 + threadIdx.x;
  if (i >= n8) return;
  const float4 a  = ((const float4*)src)[2 * (size_t)i];
  const float4 b2 = ((const float4*)src)[2 * (size_t)i + 1];
  uint4 o;
  o.x = f2bf(a.x)  | ((unsigned)f2bf(a.y)  << 16);
  o.y = f2bf(a.z)  | ((unsigned)f2bf(a.w)  << 16);
  o.z = f2bf(b2.x) | ((unsigned)f2bf(b2.y) << 16);
  o.w = f2bf(b2.z) | ((unsigned)f2bf(b2.w) << 16);
  ((uint4*)dst)[i] = o;
}

// ===== weights fp32 -> bf16 =====
__global__ void cvtw_k(const float* __restrict__ w0, const float* __restrict__ w1,
                       const float* __restrict__ w2, const float* __restrict__ w3,
                       unsigned short* __restrict__ out)
{
  const int seg = blockIdx.y;
  const float* src = (seg == 0) ? w0 : ((seg == 1) ? w1 : ((seg == 2) ? w2 : w3));
  unsigned short* dst = out + (size_t)seg * 1024 * 1024;
  const int i = blockIdx.x * 256 + threadIdx.x;   // 131072 chunks of 8
  const float4 a  = ((const float4*)src)[2 * (size_t)i];
  const float4 b2 = ((const float4*)src)[2 * (size_t)i + 1];
  uint4 o;
  o.x = f2bf(a.x)  | ((unsigned)f2bf(a.y)  << 16);
  o.y = f2bf(a.z)  | ((unsigned)f2bf(a.w)  << 16);
  o.z = f2bf(b2.x) | ((unsigned)f2bf(b2.y) << 16);
  o.w = f2bf(b2.z) | ((unsigned)f2bf(b2.w) << 16);
  ((uint4*)dst)[i] = o;
}

// ===== GEMM core: C_tile = A @ W^T (+bias)(+resid) =====
// A [M,1024] bf16, W [1024,1024] bf16. 128x128 tile, BK=64, 4 waves (2x2 of 64x64).
// Both operands staged via global_load_lds, linear LDS (m97-verified).
// MODE 0: bf16 out, permuted [B,H,S,D], scaled. MODE 1: f32 out + bias + residual.
template<int MODE>
__device__ __forceinline__
void gemm_body(unsigned short* sA, unsigned short* sB,
               const unsigned short* __restrict__ A, const unsigned short* __restrict__ Bw,
               const float* __restrict__ bias, void* __restrict__ Cout,
               const float* __restrict__ resid, int Slog, float scale, int bm, int bn)
{
  const int tid = threadIdx.x;
  const int lane = tid & 63, w = tid >> 6;
  const int g = lane >> 4, lr = lane & 15;
  const int wm = w >> 1, wn = w & 1;

  f32x4 acc[4][4] = {};

  for (int k0 = 0; k0 < 1024; k0 += 64) {
#pragma unroll
    for (int i = 0; i < 4; ++i) {
      const int chunk = (i * 4 + w) * 64 + lane;   // 0..1023
      const int o = chunk * 16;                    // linear LDS byte offset
      const int row = o >> 7;                      // 128B per row
      const int c2 = (o & 127) >> 1;               // element col within row
      async_copy16(A  + (size_t)(bm + row) * 1024 + k0 + c2, sA + (i * 4 + w) * 512);
      async_copy16(Bw + (size_t)(bn + row) * 1024 + k0 + c2, sB + (i * 4 + w) * 512);
    }
    __syncthreads();
#pragma unroll
    for (int kc = 0; kc < 2; ++kc) {
      const int kb = kc * 64 + g * 16;             // byte offset within 128B row
      bf16x8 af[4], bf[4];
#pragma unroll
      for (int mi = 0; mi < 4; ++mi) {
        const int r = wm * 64 + mi * 16 + lr;
        af[mi] = *(const bf16x8*)((const char*)sA + ((r << 7) | kb));
      }
#pragma unroll
      for (int ni = 0; ni < 4; ++ni) {
        const int r = wn * 64 + ni * 16 + lr;
        bf[ni] = *(const bf16x8*)((const char*)sB + ((r << 7) | kb));
      }
#pragma unroll
      for (int mi = 0; mi < 4; ++mi)
#pragma unroll
        for (int ni = 0; ni < 4; ++ni)
          acc[mi][ni] = __builtin_amdgcn_mfma_f32_16x16x32_bf16(af[mi], bf[ni], acc[mi][ni], 0, 0, 0);
    }
    __syncthreads();
  }

  if (MODE == 0) {
    unsigned short* O = (unsigned short*)Cout;
    const int S = 1 << Slog;
#pragma unroll
    for (int ni = 0; ni < 4; ++ni) {
      const int col = bn + wn * 64 + ni * 16 + lr;
      const float bv = bias[col];
      const int hh = col >> 6, d = col & 63;
#pragma unroll
      for (int mi = 0; mi < 4; ++mi) {
#pragma unroll
        for (int j = 0; j < 4; ++j) {
          const int row = bm + wm * 64 + mi * 16 + g * 4 + j;
          const int bI = row >> Slog, s2 = row & (S - 1);
          O[(((size_t)(bI * NH + hh)) * S + s2) * HD + d] = f2bf((acc[mi][ni][j] + bv) * scale);
        }
      }
    }
  } else {
    float* O = (float*)Cout;
#pragma unroll
    for (int ni = 0; ni < 4; ++ni) {
      const int col = bn + wn * 64 + ni * 16 + lr;
      const float bv = bias[col];
#pragma unroll
      for (int mi = 0; mi < 4; ++mi) {
#pragma unroll
        for (int j = 0; j < 4; ++j) {
          const int row = bm + wm * 64 + mi * 16 + g * 4 + j;
          const size_t idx = (size_t)row * 1024 + col;
          O[idx] = acc[mi][ni][j] + bv + resid[idx];
        }
      }
    }
  }
}

// Merged Q/K/V projection: blockIdx.z selects segment. Q uses 32 x-blocks, K/V 64.
__global__ __launch_bounds__(256, 2)
void proj3_k(const unsigned short* __restrict__ qb, const unsigned short* __restrict__ kb,
             const unsigned short* __restrict__ vb, const unsigned short* __restrict__ Wb,
             const float* __restrict__ bq, const float* __restrict__ bk,
             const float* __restrict__ bv, unsigned short* __restrict__ Qp,
             unsigned short* __restrict__ Kp, unsigned short* __restrict__ Vp)
{
  __shared__ __attribute__((aligned(16))) unsigned short sA[128 * 64];
  __shared__ __attribute__((aligned(16))) unsigned short sB[128 * 64];
  const int seg = blockIdx.z;
  if (seg == 0 && blockIdx.x >= 32) return;   // uniform per-workgroup exit
  const unsigned short* A   = (seg == 0) ? qb : ((seg == 1) ? kb : vb);
  const unsigned short* W   = Wb + ((size_t)seg << 20);
  const float*          bia = (seg == 0) ? bq : ((seg == 1) ? bk : bv);
  unsigned short*       O   = (seg == 0) ? Qp : ((seg == 1) ? Kp : Vp);
  const int   Slog  = (seg == 0) ? 10 : 11;
  const float scale = (seg == 0) ? 0.125f : 1.0f;
  gemm_body<0>(sA, sB, A, W, bia, O, nullptr, Slog, scale, blockIdx.x * 128, blockIdx.y * 128);
}

// Out projection + bias + residual (f32 out)
__global__ __launch_bounds__(256, 2)
void gemm_o_k(const unsigned short* __restrict__ ctx, const unsigned short* __restrict__ Wo,
              const float* __restrict__ bo, float* __restrict__ xb,
              const float* __restrict__ resid)
{
  __shared__ __attribute__((aligned(16))) unsigned short sA[128 * 64];
  __shared__ __attribute__((aligned(16))) unsigned short sB[128 * 64];
  gemm_body<1>(sA, sB, ctx, Wo, bo, xb, resid, 10, 1.0f, blockIdx.x * 128, blockIdx.y * 128);
}

// ===== MFMA flash attention =====
// K tile XOR-swizzled (rule #21 both-sides: linear LDS dest + inverse-swizzled
// global source + swizzled ds_read). P round-trip: bf16-typed LDS + barrier
// between softmax writes and PV reads (the round-1/2 TBAA/ordering bug fix).
__global__ __launch_bounds__(256, 2)
void attn_k(const unsigned short* __restrict__ Qp, const unsigned short* __restrict__ Kp,
            const unsigned short* __restrict__ Vp, unsigned short* __restrict__ ctx)
{
  __shared__ __attribute__((aligned(16))) unsigned short sK[128 * 64];
  __shared__ __attribute__((aligned(16))) __bf16 sVt[64 * 136];
  __shared__ __attribute__((aligned(16))) __bf16 sP[4][32 * 136];

  const int tid = threadIdx.x, lane = tid & 63, w = tid >> 6;
  const int g = lane >> 4, lr = lane & 15;
  const int b = blockIdx.z, h = blockIdx.y;
  const int q0 = blockIdx.x * 128 + w * 32;
  const size_t qbase  = ((size_t)(b * NH + h)) * SQL * HD;
  const size_t kvbase = ((size_t)(b * NH + h)) * SKL * HD;

  // Q fragments live in registers (pre-scaled by 1/8 at projection)
  bf16x8 aq[2][2];
#pragma unroll
  for (int mi = 0; mi < 2; ++mi)
#pragma unroll
    for (int kc = 0; kc < 2; ++kc)
      aq[mi][kc] = *(const bf16x8*)(Qp + qbase + (size_t)(q0 + mi * 16 + lr) * HD + kc * 32 + g * 8);

  f32x4 c[2][4] = {};
  float mrun[2][4], lrun[2][4];
#pragma unroll
  for (int mi = 0; mi < 2; ++mi)
#pragma unroll
    for (int j = 0; j < 4; ++j) { mrun[mi][j] = -__builtin_inff(); lrun[mi][j] = 0.f; }

  for (int kt = 0; kt < SKL / 128; ++kt) {
    // stage K tile [128][64], XOR-swizzled via pre-swizzled global source
#pragma unroll
    for (int i = 0; i < 4; ++i) {
      const int chunk = (i * 4 + w) * 64 + lane;
      const int o = chunk * 16;
      const int row = o >> 7;
      const int colb = (o & 127) ^ ((row & 7) << 4);  // inverse-swizzled source col (bytes)
      async_copy16(Kp + kvbase + (size_t)(kt * 128 + row) * HD + (colb >> 1),
                   sK + (i * 4 + w) * 512);
    }
    // stage V transposed: sVt[d][k], padded stride 136
#pragma unroll
    for (int i = 0; i < 4; ++i) {
      const int chunk = i * 256 + tid;
      const int k = chunk & 127, dblk = chunk >> 7;
      bf16x8 v = *(const bf16x8*)(Vp + kvbase + (size_t)(kt * 128 + k) * HD + dblk * 8);
#pragma unroll
      for (int j = 0; j < 8; ++j)
        sVt[(dblk * 8 + j) * 136 + k] = v[j];
    }
    __syncthreads();   // staging visible (drains global_load_lds too)

    // S = Q K^T, 32 q-rows x 128 k-cols per wave; swizzled sK read
    f32x4 s[2][8] = {};
#pragma unroll
    for (int kc = 0; kc < 2; ++kc) {
      const int kb = kc * 64 + g * 16;
#pragma unroll
      for (int ni = 0; ni < 8; ++ni) {
        const int r = ni * 16 + lr;
        bf16x8 bk = *(const bf16x8*)((const char*)sK + ((r << 7) | (kb ^ ((r & 7) << 4))));
        s[0][ni] = __builtin_amdgcn_mfma_f32_16x16x32_bf16(aq[0][kc], bk, s[0][ni], 0, 0, 0);
        s[1][ni] = __builtin_amdgcn_mfma_f32_16x16x32_bf16(aq[1][kc], bk, s[1][ni], 0, 0, 0);
      }
    }

    // online softmax, wave-parallel (row = mi*16 + 4g + j; 16 lanes lr share a row)
#pragma unroll
    for (int mi = 0; mi < 2; ++mi) {
#pragma unroll
      for (int j = 0; j < 4; ++j) {
        float rm = s[mi][0][j];
#pragma unroll
        for (int ni = 1; ni < 8; ++ni) rm = fmaxf(rm, s[mi][ni][j]);
#pragma unroll
        for (int off = 1; off < 16; off <<= 1) rm = fmaxf(rm, __shfl_xor(rm, off));
        const float mnew = fmaxf(mrun[mi][j], rm);
        const float sc = __builtin_exp2f((mrun[mi][j] - mnew) * LOG2E);
        mrun[mi][j] = mnew;
#pragma unroll
        for (int nd = 0; nd < 4; ++nd) c[mi][nd][j] *= sc;
        float rs = 0.f;
#pragma unroll
        for (int ni = 0; ni < 8; ++ni) {
          const float p = __builtin_exp2f((s[mi][ni][j] - mnew) * LOG2E);
          rs += p;
          sP[w][(mi * 16 + g * 4 + j) * 136 + ni * 16 + lr] = f2bf16(p);
        }
#pragma unroll
        for (int off = 1; off < 16; off <<= 1) rs += __shfl_xor(rs, off);
        lrun[mi][j] = lrun[mi][j] * sc + rs;
      }
    }
    __syncthreads();   // order P writes before PV reads

    // ctx += P @ V
#pragma unroll
    for (int kc = 0; kc < 4; ++kc) {
      const int ko = kc * 32 + g * 8;
      bf16x8 pa[2];
#pragma unroll
      for (int mi = 0; mi < 2; ++mi)
        pa[mi] = *(const bf16x8*)(&sP[w][(mi * 16 + lr) * 136 + ko]);
#pragma unroll
      for (int nd = 0; nd < 4; ++nd) {
        bf16x8 vf = *(const bf16x8*)(&sVt[(nd * 16 + lr) * 136 + ko]);
        c[0][nd] = __builtin_amdgcn_mfma_f32_16x16x32_bf16(pa[0], vf, c[0][nd], 0, 0, 0);
        c[1][nd] = __builtin_amdgcn_mfma_f32_16x16x32_bf16(pa[1], vf, c[1][nd], 0, 0, 0);
      }
    }
    __syncthreads();   // protect sK/sVt before next iteration's staging
  }

  // finalize: ctx / l, write [B, SQ, E] bf16
#pragma unroll
  for (int mi = 0; mi < 2; ++mi)
#pragma unroll
    for (int j = 0; j < 4; ++j) {
      const float inv = 1.0f / lrun[mi][j];
      const int qrow = q0 + mi * 16 + g * 4 + j;
#pragma unroll
      for (int nd = 0; nd < 4; ++nd) {
        const int d = nd * 16 + lr;
        ctx[((size_t)b * SQL + qrow) * EMB + h * HD + d] = f2bf(c[mi][nd][j] * inv);
      }
    }
}

// ===== residual + LayerNorm: one block per row of 1024 =====
__global__ __launch_bounds__(256)
void ln_k(const float* __restrict__ x, const float* __restrict__ gm,
          const float* __restrict__ bt, float* __restrict__ out)
{
  const int row = blockIdx.x, t = threadIdx.x;
  const float4 v = ((const float4*)(x + (size_t)row * 1024))[t];
  float s  = v.x + v.y + v.z + v.w;
  float ss = v.x * v.x + v.y * v.y + v.z * v.z + v.w * v.w;
#pragma unroll
  for (int off = 32; off > 0; off >>= 1) {
    s  += __shfl_xor(s, off);
    ss += __shfl_xor(ss, off);
  }
  __shared__ float red[8];
  const int wv = t >> 6, lane = t & 63;
  if (lane == 0) { red[wv] = s; red[4 + wv] = ss; }
  __syncthreads();
  s  = red[0] + red[1] + red[2] + red[3];
  ss = red[4] + red[5] + red[6] + red[7];
  const float mu  = s * (1.0f / 1024.0f);
  const float var = ss * (1.0f / 1024.0f) - mu * mu;
  const float r = rsqrtf(var + 1e-5f);
  const float4 gg = ((const float4*)gm)[t];
  const float4 bb = ((const float4*)bt)[t];
  float4 o;
  o.x = (v.x - mu) * r * gg.x + bb.x;
  o.y = (v.y - mu) * r * gg.y + bb.y;
  o.z = (v.z - mu) * r * gg.z + bb.z;
  o.w = (v.w - mu) * r * gg.w + bb.w;
  ((float4*)(out + (size_t)row * 1024))[t] = o;
}

extern "C" void kernel_launch(void* const* d_in, const int* in_sizes, int n_in,
                              void* d_out, int out_size, void* d_ws, size_t ws_size,
                              hipStream_t stream)
{
  (void)in_sizes; (void)n_in; (void)out_size; (void)ws_size;
  const float* query = (const float*)d_in[0];
  const float* key   = (const float*)d_in[1];
  const float* value = (const float*)d_in[2];
  const float* Wq = (const float*)d_in[3];
  const float* bq = (const float*)d_in[4];
  const float* Wk = (const float*)d_in[5];
  const float* bk = (const float*)d_in[6];
  const float* Wv = (const float*)d_in[7];
  const float* bv = (const float*)d_in[8];
  const float* Wo = (const float*)d_in[9];
  const float* bo = (const float*)d_in[10];
  const float* gamma = (const float*)d_in[11];
  const float* beta  = (const float*)d_in[12];

  // workspace layout (peak 88 MB; rounds 1-2 ran fine at 88 MB):
  // [0,8M):   Wb  (4 weights bf16)
  // [8,16M):  qb bf16           -- dead after Q-proj; reused as ctx bf16 [B,SQ,E]
  // [16,32M): kb bf16           -- dead after K-proj; reused as xb f32 [8..24M window]
  // [32,48M): vb bf16
  // [48,56M): Qp | [56,72M): Kp | [72,88M): Vp
  char* ws = (char*)d_ws;
  unsigned short* Wb  = (unsigned short*)(ws);
  unsigned short* qb  = (unsigned short*)(ws + (8ull  << 20));
  unsigned short* ctx = qb;
  unsigned short* kb  = (unsigned short*)(ws + (16ull << 20));
  float*          xb  = (float*)         (ws + (16ull << 20));
  unsigned short* vb  = (unsigned short*)(ws + (32ull << 20));
  unsigned short* Qp  = (unsigned short*)(ws + (48ull << 20));
  unsigned short* Kp  = (unsigned short*)(ws + (56ull << 20));
  unsigned short* Vp  = (unsigned short*)(ws + (72ull << 20));

  cvt3_k<<<dim3(4096, 3), 256, 0, stream>>>(query, key, value, qb, kb, vb);
  cvtw_k<<<dim3(512, 4),  256, 0, stream>>>(Wq, Wk, Wv, Wo, Wb);
  // merged projections (Q pre-scaled by 1/sqrt(HD)=0.125)
  proj3_k<<<dim3(64, 8, 3), 256, 0, stream>>>(qb, kb, vb, Wb, bq, bk, bv, Qp, Kp, Vp);
  attn_k<<<dim3(8, NH, 4), 256, 0, stream>>>(Qp, Kp, Vp, ctx);
  // out projection + bias + residual (f32)
  gemm_o_k<<<dim3(32, 8), 256, 0, stream>>>(ctx, Wb + (3u << 20), bo, xb, query);
  ln_k<<<dim3(4096), 256, 0, stream>>>(xb, gamma, beta, (float*)d_out);
}

// Round 6
// 343.680 us; speedup vs baseline: 4.1103x; 1.1505x over previous
//
#include <hip/hip_runtime.h>

// ===== problem constants =====
#define NH   16
#define HD   64
#define SQL  1024
#define SKL  2048
#define EMB  1024

typedef __bf16 bf16x8 __attribute__((ext_vector_type(8)));
typedef float  f32x4  __attribute__((ext_vector_type(4)));

#define LOG2E 1.44269504088896f
#define PSTR  132   // padded stride for sVt/sP (2-way-free banks both sides)

__device__ __forceinline__ unsigned short f2bf(float f) {
  unsigned u = __builtin_bit_cast(unsigned, f);
  u += 0x7FFFu + ((u >> 16) & 1u);   // round-to-nearest-even
  return (unsigned short)(u >> 16);
}
__device__ __forceinline__ __bf16 f2bf16(float f) {
  return __builtin_bit_cast(__bf16, f2bf(f));
}

typedef __attribute__((address_space(1))) void gvoid_t;
typedef __attribute__((address_space(3))) void lvoid_t;

// async global->LDS, 16B per lane, dest = wave-uniform base + lane*16 (m97 pattern)
__device__ __forceinline__ void async_copy16(const void* g, void* l) {
  __builtin_amdgcn_global_load_lds((gvoid_t*)g, (lvoid_t*)l, 16, 0, 0);
}

// ===== activations fp32 -> bf16 =====
__global__ void cvt3_k(const float* __restrict__ q, const float* __restrict__ k,
                       const float* __restrict__ v, unsigned short* __restrict__ qb,
                       unsigned short* __restrict__ kb, unsigned short* __restrict__ vb)
{
  const int seg = blockIdx.y;
  const float* src = (seg == 0) ? q : ((seg == 1) ? k : v);
  unsigned short* dst = (seg == 0) ? qb : ((seg == 1) ? kb : vb);
  const int n8 = (seg == 0) ? (4 * 1024 * 1024 / 8) : (8 * 1024 * 1024 / 8);
  const int i = blockIdx.x * 256 + threadIdx.x;
  if (i >= n8) return;
  const float4 a  = ((const float4*)src)[2 * (size_t)i];
  const float4 b2 = ((const float4*)src)[2 * (size_t)i + 1];
  uint4 o;
  o.x = f2bf(a.x)  | ((unsigned)f2bf(a.y)  << 16);
  o.y = f2bf(a.z)  | ((unsigned)f2bf(a.w)  << 16);
  o.z = f2bf(b2.x) | ((unsigned)f2bf(b2.y) << 16);
  o.w = f2bf(b2.z) | ((unsigned)f2bf(b2.w) << 16);
  ((uint4*)dst)[i] = o;
}

// ===== weights fp32 -> bf16 =====
__global__ void cvtw_k(const float* __restrict__ w0, const float* __restrict__ w1,
                       const float* __restrict__ w2, const float* __restrict__ w3,
                       unsigned short* __restrict__ out)
{
  const int seg = blockIdx.y;
  const float* src = (seg == 0) ? w0 : ((seg == 1) ? w1 : ((seg == 2) ? w2 : w3));
  unsigned short* dst = out + (size_t)seg * 1024 * 1024;
  const int i = blockIdx.x * 256 + threadIdx.x;   // 131072 chunks of 8
  const float4 a  = ((const float4*)src)[2 * (size_t)i];
  const float4 b2 = ((const float4*)src)[2 * (size_t)i + 1];
  uint4 o;
  o.x = f2bf(a.x)  | ((unsigned)f2bf(a.y)  << 16);
  o.y = f2bf(a.z)  | ((unsigned)f2bf(a.w)  << 16);
  o.z = f2bf(b2.x) | ((unsigned)f2bf(b2.y) << 16);
  o.w = f2bf(b2.z) | ((unsigned)f2bf(b2.w) << 16);
  ((uint4*)dst)[i] = o;
}

// ===== GEMM core: C_tile = A @ W^T (+bias)(+resid) =====  (UNCHANGED, passing)
template<int MODE>
__device__ __forceinline__
void gemm_body(unsigned short* sA, unsigned short* sB,
               const unsigned short* __restrict__ A, const unsigned short* __restrict__ Bw,
               const float* __restrict__ bias, void* __restrict__ Cout,
               const float* __restrict__ resid, int Slog, float scale, int bm, int bn)
{
  const int tid = threadIdx.x;
  const int lane = tid & 63, w = tid >> 6;
  const int g = lane >> 4, lr = lane & 15;
  const int wm = w >> 1, wn = w & 1;

  f32x4 acc[4][4] = {};

  for (int k0 = 0; k0 < 1024; k0 += 64) {
#pragma unroll
    for (int i = 0; i < 4; ++i) {
      const int chunk = (i * 4 + w) * 64 + lane;   // 0..1023
      const int o = chunk * 16;                    // linear LDS byte offset
      const int row = o >> 7;                      // 128B per row
      const int c2 = (o & 127) >> 1;               // element col within row
      async_copy16(A  + (size_t)(bm + row) * 1024 + k0 + c2, sA + (i * 4 + w) * 512);
      async_copy16(Bw + (size_t)(bn + row) * 1024 + k0 + c2, sB + (i * 4 + w) * 512);
    }
    __syncthreads();
#pragma unroll
    for (int kc = 0; kc < 2; ++kc) {
      const int kb = kc * 64 + g * 16;             // byte offset within 128B row
      bf16x8 af[4], bf[4];
#pragma unroll
      for (int mi = 0; mi < 4; ++mi) {
        const int r = wm * 64 + mi * 16 + lr;
        af[mi] = *(const bf16x8*)((const char*)sA + ((r << 7) | kb));
      }
#pragma unroll
      for (int ni = 0; ni < 4; ++ni) {
        const int r = wn * 64 + ni * 16 + lr;
        bf[ni] = *(const bf16x8*)((const char*)sB + ((r << 7) | kb));
      }
#pragma unroll
      for (int mi = 0; mi < 4; ++mi)
#pragma unroll
        for (int ni = 0; ni < 4; ++ni)
          acc[mi][ni] = __builtin_amdgcn_mfma_f32_16x16x32_bf16(af[mi], bf[ni], acc[mi][ni], 0, 0, 0);
    }
    __syncthreads();
  }

  if (MODE == 0) {
    unsigned short* O = (unsigned short*)Cout;
    const int S = 1 << Slog;
#pragma unroll
    for (int ni = 0; ni < 4; ++ni) {
      const int col = bn + wn * 64 + ni * 16 + lr;
      const float bv = bias[col];
      const int hh = col >> 6, d = col & 63;
#pragma unroll
      for (int mi = 0; mi < 4; ++mi) {
#pragma unroll
        for (int j = 0; j < 4; ++j) {
          const int row = bm + wm * 64 + mi * 16 + g * 4 + j;
          const int bI = row >> Slog, s2 = row & (S - 1);
          O[(((size_t)(bI * NH + hh)) * S + s2) * HD + d] = f2bf((acc[mi][ni][j] + bv) * scale);
        }
      }
    }
  } else {
    float* O = (float*)Cout;
#pragma unroll
    for (int ni = 0; ni < 4; ++ni) {
      const int col = bn + wn * 64 + ni * 16 + lr;
      const float bv = bias[col];
#pragma unroll
      for (int mi = 0; mi < 4; ++mi) {
#pragma unroll
        for (int j = 0; j < 4; ++j) {
          const int row = bm + wm * 64 + mi * 16 + g * 4 + j;
          const size_t idx = (size_t)row * 1024 + col;
          O[idx] = acc[mi][ni][j] + bv + resid[idx];
        }
      }
    }
  }
}

// Merged Q/K/V projection: blockIdx.z selects segment. Q uses 32 x-blocks, K/V 64.
__global__ __launch_bounds__(256, 2)
void proj3_k(const unsigned short* __restrict__ qb, const unsigned short* __restrict__ kb,
             const unsigned short* __restrict__ vb, const unsigned short* __restrict__ Wb,
             const float* __restrict__ bq, const float* __restrict__ bk,
             const float* __restrict__ bv, unsigned short* __restrict__ Qp,
             unsigned short* __restrict__ Kp, unsigned short* __restrict__ Vp)
{
  __shared__ __attribute__((aligned(16))) unsigned short sA[128 * 64];
  __shared__ __attribute__((aligned(16))) unsigned short sB[128 * 64];
  const int seg = blockIdx.z;
  if (seg == 0 && blockIdx.x >= 32) return;   // uniform per-workgroup exit
  const unsigned short* A   = (seg == 0) ? qb : ((seg == 1) ? kb : vb);
  const unsigned short* W   = Wb + ((size_t)seg << 20);
  const float*          bia = (seg == 0) ? bq : ((seg == 1) ? bk : bv);
  unsigned short*       O   = (seg == 0) ? Qp : ((seg == 1) ? Kp : Vp);
  const int   Slog  = (seg == 0) ? 10 : 11;
  const float scale = (seg == 0) ? 0.125f : 1.0f;
  gemm_body<0>(sA, sB, A, W, bia, O, nullptr, Slog, scale, blockIdx.x * 128, blockIdx.y * 128);
}

// Out projection + bias + residual (f32 out)
__global__ __launch_bounds__(256, 2)
void gemm_o_k(const unsigned short* __restrict__ ctx, const unsigned short* __restrict__ Wo,
              const float* __restrict__ bo, float* __restrict__ xb,
              const float* __restrict__ resid)
{
  __shared__ __attribute__((aligned(16))) unsigned short sA[128 * 64];
  __shared__ __attribute__((aligned(16))) unsigned short sB[128 * 64];
  gemm_body<1>(sA, sB, ctx, Wo, bo, xb, resid, 10, 1.0f, blockIdx.x * 128, blockIdx.y * 128);
}

// ===== MFMA flash attention =====
// r6: (1) XCD-grouped (b,h) mapping (8 q-blocks of a head share an XCD's L2);
//     (2) T14 K+V reg-prefetch for kt+1 issued after barrier-1 of kt (HBM latency
//         hidden under QK^T+softmax+PV); K swizzle moved to ds_write side
//         (identical sK layout, read path unchanged);
//     (3) sVt/sP stride 136->132 (P-write 4-way bank aliasing -> 2-way free).
__global__ __launch_bounds__(256, 2)
void attn_k(const unsigned short* __restrict__ Qp, const unsigned short* __restrict__ Kp,
            const unsigned short* __restrict__ Vp, unsigned short* __restrict__ ctx)
{
  __shared__ __attribute__((aligned(16))) unsigned short sK[128 * 64];
  __shared__ __attribute__((aligned(16))) __bf16 sVt[64 * PSTR];
  __shared__ __attribute__((aligned(16))) __bf16 sP[4][32 * PSTR];

  const int tid = threadIdx.x, lane = tid & 63, w = tid >> 6;
  const int g = lane >> 4, lr = lane & 15;

  // XCD-grouped decomposition: 64 (b,h) pairs over 8 XCDs, 8 q-blocks each.
  const int id  = blockIdx.x;          // 0..511, XCD = id & 7 (round-robin dispatch)
  const int xcd = id & 7, t = id >> 3;
  const int bh  = xcd * 8 + (t >> 3);  // 8 heads' worth of KV per XCD (~4MB = L2)
  const int qb  = t & 7;
  const int b = bh >> 4, h = bh & 15;
  const int q0 = qb * 128 + w * 32;
  const size_t qbase  = ((size_t)(b * NH + h)) * SQL * HD;
  const size_t kvbase = ((size_t)(b * NH + h)) * SKL * HD;

  // Q fragments live in registers (pre-scaled by 1/8 at projection)
  bf16x8 aq[2][2];
#pragma unroll
  for (int mi = 0; mi < 2; ++mi)
#pragma unroll
    for (int kc = 0; kc < 2; ++kc)
      aq[mi][kc] = *(const bf16x8*)(Qp + qbase + (size_t)(q0 + mi * 16 + lr) * HD + kc * 32 + g * 8);

  f32x4 c[2][4] = {};
  float mrun[2][4], lrun[2][4];
#pragma unroll
  for (int mi = 0; mi < 2; ++mi)
#pragma unroll
    for (int j = 0; j < 4; ++j) { mrun[mi][j] = -__builtin_inff(); lrun[mi][j] = 0.f; }

  // ---- prefetch registers for tile kt (K: linear chunks; V: k-fast chunks) ----
  bf16x8 kA[4], vA[4];
#pragma unroll
  for (int i = 0; i < 4; ++i) {
    const int c = i * 256 + tid;
    kA[i] = *(const bf16x8*)(Kp + kvbase + (size_t)c * 8);                      // row=c>>3, colb=(c&7)*16
    vA[i] = *(const bf16x8*)(Vp + kvbase + (size_t)(c & 127) * HD + (c >> 7) * 8); // k=c&127, dblk=c>>7
  }

  for (int kt = 0; kt < SKL / 128; ++kt) {
    // ---- write prefetched K tile to sK, swizzled on the write side ----
#pragma unroll
    for (int i = 0; i < 4; ++i) {
      const int cc = i * 256 + tid;
      const int row = cc >> 3, cb = (cc & 7) * 16;
      *(bf16x8*)((char*)sK + ((row << 7) | (cb ^ ((row & 7) << 4)))) = kA[i];
    }
    // ---- write prefetched V tile transposed: sVt[d][k] ----
#pragma unroll
    for (int i = 0; i < 4; ++i) {
      const int cc = i * 256 + tid;
      const int k = cc & 127, dblk = cc >> 7;
#pragma unroll
      for (int j = 0; j < 8; ++j)
        sVt[(dblk * 8 + j) * PSTR + k] = vA[i][j];
    }
    __syncthreads();   // barrier 1: staging visible

    // ---- T14: issue next tile's global loads; consumed after barrier 3 ----
    if (kt + 1 < SKL / 128) {
      const size_t nb = kvbase + (size_t)(kt + 1) * 128 * HD;
#pragma unroll
      for (int i = 0; i < 4; ++i) {
        const int cc = i * 256 + tid;
        kA[i] = *(const bf16x8*)(Kp + nb + (size_t)cc * 8);
        vA[i] = *(const bf16x8*)(Vp + nb + (size_t)(cc & 127) * HD + (cc >> 7) * 8);
      }
    }

    // ---- S = Q K^T, 32 q-rows x 128 k-cols per wave; swizzled sK read ----
    f32x4 s[2][8] = {};
#pragma unroll
    for (int kc = 0; kc < 2; ++kc) {
      const int kb = kc * 64 + g * 16;
#pragma unroll
      for (int ni = 0; ni < 8; ++ni) {
        const int r = ni * 16 + lr;
        bf16x8 bk = *(const bf16x8*)((const char*)sK + ((r << 7) | (kb ^ ((r & 7) << 4))));
        s[0][ni] = __builtin_amdgcn_mfma_f32_16x16x32_bf16(aq[0][kc], bk, s[0][ni], 0, 0, 0);
        s[1][ni] = __builtin_amdgcn_mfma_f32_16x16x32_bf16(aq[1][kc], bk, s[1][ni], 0, 0, 0);
      }
    }

    // ---- online softmax, wave-parallel (row = mi*16 + 4g + j) ----
#pragma unroll
    for (int mi = 0; mi < 2; ++mi) {
#pragma unroll
      for (int j = 0; j < 4; ++j) {
        float rm = s[mi][0][j];
#pragma unroll
        for (int ni = 1; ni < 8; ++ni) rm = fmaxf(rm, s[mi][ni][j]);
#pragma unroll
        for (int off = 1; off < 16; off <<= 1) rm = fmaxf(rm, __shfl_xor(rm, off));
        const float mnew = fmaxf(mrun[mi][j], rm);
        const float sc = __builtin_exp2f((mrun[mi][j] - mnew) * LOG2E);
        mrun[mi][j] = mnew;
#pragma unroll
        for (int nd = 0; nd < 4; ++nd) c[mi][nd][j] *= sc;
        float rs = 0.f;
#pragma unroll
        for (int ni = 0; ni < 8; ++ni) {
          const float p = __builtin_exp2f((s[mi][ni][j] - mnew) * LOG2E);
          rs += p;
          sP[w][(mi * 16 + g * 4 + j) * PSTR + ni * 16 + lr] = f2bf16(p);
        }
#pragma unroll
        for (int off = 1; off < 16; off <<= 1) rs += __shfl_xor(rs, off);
        lrun[mi][j] = lrun[mi][j] * sc + rs;
      }
    }
    __syncthreads();   // barrier 2: order P writes before PV reads

    // ---- ctx += P @ V ----
#pragma unroll
    for (int kc = 0; kc < 4; ++kc) {
      const int ko = kc * 32 + g * 8;
      bf16x8 pa[2];
#pragma unroll
      for (int mi = 0; mi < 2; ++mi)
        pa[mi] = *(const bf16x8*)(&sP[w][(mi * 16 + lr) * PSTR + ko]);
#pragma unroll
      for (int nd = 0; nd < 4; ++nd) {
        bf16x8 vf = *(const bf16x8*)(&sVt[(nd * 16 + lr) * PSTR + ko]);
        c[0][nd] = __builtin_amdgcn_mfma_f32_16x16x32_bf16(pa[0], vf, c[0][nd], 0, 0, 0);
        c[1][nd] = __builtin_amdgcn_mfma_f32_16x16x32_bf16(pa[1], vf, c[1][nd], 0, 0, 0);
      }
    }
    __syncthreads();   // barrier 3: PV LDS reads done before next overwrite
  }

  // finalize: ctx / l, write [B, SQ, E] bf16
#pragma unroll
  for (int mi = 0; mi < 2; ++mi)
#pragma unroll
    for (int j = 0; j < 4; ++j) {
      const float inv = 1.0f / lrun[mi][j];
      const int qrow = q0 + mi * 16 + g * 4 + j;
#pragma unroll
      for (int nd = 0; nd < 4; ++nd) {
        const int d = nd * 16 + lr;
        ctx[((size_t)b * SQL + qrow) * EMB + h * HD + d] = f2bf(c[mi][nd][j] * inv);
      }
    }
}

// ===== residual + LayerNorm: one block per row of 1024 =====
__global__ __launch_bounds__(256)
void ln_k(const float* __restrict__ x, const float* __restrict__ gm,
          const float* __restrict__ bt, float* __restrict__ out)
{
  const int row = blockIdx.x, t = threadIdx.x;
  const float4 v = ((const float4*)(x + (size_t)row * 1024))[t];
  float s  = v.x + v.y + v.z + v.w;
  float ss = v.x * v.x + v.y * v.y + v.z * v.z + v.w * v.w;
#pragma unroll
  for (int off = 32; off > 0; off >>= 1) {
    s  += __shfl_xor(s, off);
    ss += __shfl_xor(ss, off);
  }
  __shared__ float red[8];
  const int wv = t >> 6, lane = t & 63;
  if (lane == 0) { red[wv] = s; red[4 + wv] = ss; }
  __syncthreads();
  s  = red[0] + red[1] + red[2] + red[3];
  ss = red[4] + red[5] + red[6] + red[7];
  const float mu  = s * (1.0f / 1024.0f);
  const float var = ss * (1.0f / 1024.0f) - mu * mu;
  const float r = rsqrtf(var + 1e-5f);
  const float4 gg = ((const float4*)gm)[t];
  const float4 bb = ((const float4*)bt)[t];
  float4 o;
  o.x = (v.x - mu) * r * gg.x + bb.x;
  o.y = (v.y - mu) * r * gg.y + bb.y;
  o.z = (v.z - mu) * r * gg.z + bb.z;
  o.w = (v.w - mu) * r * gg.w + bb.w;
  ((float4*)(out + (size_t)row * 1024))[t] = o;
}

extern "C" void kernel_launch(void* const* d_in, const int* in_sizes, int n_in,
                              void* d_out, int out_size, void* d_ws, size_t ws_size,
                              hipStream_t stream)
{
  (void)in_sizes; (void)n_in; (void)out_size; (void)ws_size;
  const float* query = (const float*)d_in[0];
  const float* key   = (const float*)d_in[1];
  const float* value = (const float*)d_in[2];
  const float* Wq = (const float*)d_in[3];
  const float* bq = (const float*)d_in[4];
  const float* Wk = (const float*)d_in[5];
  const float* bk = (const float*)d_in[6];
  const float* Wv = (const float*)d_in[7];
  const float* bv = (const float*)d_in[8];
  const float* Wo = (const float*)d_in[9];
  const float* bo = (const float*)d_in[10];
  const float* gamma = (const float*)d_in[11];
  const float* beta  = (const float*)d_in[12];

  // workspace layout (peak 88 MB):
  // [0,8M):   Wb  (4 weights bf16)
  // [8,16M):  qb bf16   -- dead after Q-proj; reused as ctx bf16 [B,SQ,E]
  // [16,32M): kb bf16   -- dead after K-proj; reused as xb f32
  // [32,48M): vb bf16
  // [48,56M): Qp | [56,72M): Kp | [72,88M): Vp
  char* ws = (char*)d_ws;
  unsigned short* Wb  = (unsigned short*)(ws);
  unsigned short* qb  = (unsigned short*)(ws + (8ull  << 20));
  unsigned short* ctx = qb;
  unsigned short* kb  = (unsigned short*)(ws + (16ull << 20));
  float*          xb  = (float*)         (ws + (16ull << 20));
  unsigned short* vb  = (unsigned short*)(ws + (32ull << 20));
  unsigned short* Qp  = (unsigned short*)(ws + (48ull << 20));
  unsigned short* Kp  = (unsigned short*)(ws + (56ull << 20));
  unsigned short* Vp  = (unsigned short*)(ws + (72ull << 20));

  cvt3_k<<<dim3(4096, 3), 256, 0, stream>>>(query, key, value, qb, kb, vb);
  cvtw_k<<<dim3(512, 4),  256, 0, stream>>>(Wq, Wk, Wv, Wo, Wb);
  // merged projections (Q pre-scaled by 1/sqrt(HD)=0.125)
  proj3_k<<<dim3(64, 8, 3), 256, 0, stream>>>(qb, kb, vb, Wb, bq, bk, bv, Qp, Kp, Vp);
  attn_k<<<dim3(512), 256, 0, stream>>>(Qp, Kp, Vp, ctx);
  // out projection + bias + residual (f32)
  gemm_o_k<<<dim3(32, 8), 256, 0, stream>>>(ctx, Wb + (3u << 20), bo, xb, query);
  ln_k<<<dim3(4096), 256, 0, stream>>>(xb, gamma, beta, (float*)d_out);
}